// Round 9
// baseline (174.936 us; speedup 1.0000x reference)
//
#include <hip/hip_runtime.h>
#include <hip/hip_bf16.h>
#include <math.h>

#define B_SZ 8192
#define I_SZ 1024
#define O_SZ 1024
#define NCP  6

typedef __attribute__((ext_vector_type(8))) short bf16x8;
typedef __attribute__((ext_vector_type(4))) float f32x4;

__device__ __forceinline__ unsigned short f2bf(float f) {
  union { float f; unsigned int u; } v; v.f = f;
  unsigned int u = v.u;
  u += 0x7FFFu + ((u >> 16) & 1u);   // round-to-nearest-even
  return (unsigned short)(u >> 16);
}

__global__ void cvt_f32_to_bf16(const float* __restrict__ src,
                                unsigned short* __restrict__ dst, int n4) {
  int idx = blockIdx.x * blockDim.x + threadIdx.x;
  int stride = gridDim.x * blockDim.x;
  for (int i = idx; i < n4; i += stride) {
    float4 v = reinterpret_cast<const float4*>(src)[i];
    ushort4 o;
    o.x = f2bf(v.x); o.y = f2bf(v.y); o.z = f2bf(v.z); o.w = f2bf(v.w);
    reinterpret_cast<ushort4*>(dst)[i] = o;
  }
}

__device__ __forceinline__ void gload_lds16(const void* g, void* l) {
  __builtin_amdgcn_global_load_lds(
      (const __attribute__((address_space(1))) void*)g,
      (__attribute__((address_space(3))) void*)l, 16, 0, 0);
}

#define BM 256
#define BN 128
#define BK 64

// out[b,o] = sum_j c[b,j] * ( sum_i W[j,o,i]*x[b,i] + bias[j,o] )
// ks-outer / j-inner restructure: the SAME x K-slab multiplies all 6 W
// chunks, so A-fragments are loaded ONCE per ks DIRECTLY from global into
// registers (x is L3-resident) and reused across j -- A never touches LDS.
// LDS carries only the W tiles (ring of 3 x 16KB slots, gload_lds linear
// dest + pre-swizzled source + XOR'd ds_read: rule #21, verified rounds
// 4-8) and the c table. part[] eliminated: per-(m,n) local p folded into
// acc immediately with a per-iter f32x4 c-read (fold FMAs ride the VALU
// pipe under the MFMA pipe).
// vmcnt ledger (issues bracket-pinned by sched_barrier(0) around each
// barrier): per iter 2 W-loads staged for iter+2; 8 A-loads at ks-top.
// At iter top: j>=2 -> vmcnt(2); j in {0,1} -> vmcnt(10) (A batch between
// W(g)'s issue and now); last iter of all -> vmcnt(0) (nothing issued
// after its W).
__global__ __launch_bounds__(512, 2) void pfl_gemm(
    const unsigned short* __restrict__ xb,
    const unsigned short* __restrict__ wb,
    const float* __restrict__ phase,
    const float* __restrict__ bias,
    float* __restrict__ out) {
  __shared__ __align__(16) unsigned short Wbuf[3][BN * BK];  // 3x16 KB
  __shared__ __align__(16) float c4[NCP][BM];                // 6 KB

  const int nbn = O_SZ / BN;  // 8
  int bid = (int)blockIdx.x;  // 256 blocks (divisible by 8)
  int swz = (bid & 7) * 32 + (bid >> 3);  // bijective XCD remap
  int brow = (swz / nbn) * BM;
  int bcol = (swz % nbn) * BN;

  int tid = (int)threadIdx.x;
  int lane = tid & 63;
  int wid = tid >> 6;        // 0..7
  int wr = wid >> 1;         // 0..3 (M)
  int wc = wid & 1;          // 0..1 (N)

  // ---- Catmull-Rom coefficients, layout [j][row] for vectorized folds ----
  if (tid < BM) {
    float ph = phase[brow + tid];
    const float two_pi = 6.2831855f;
    float pm = fmodf(ph, two_pi);              // ph >= 0 -> trunc == floor mod
    float pos = pm * (float)(6.0 / 6.283185307179586);
    float base = floorf(pos);
    int bi = (int)base;
    float t = pos - base;
    float t2 = t * t, t3 = t2 * t;
    float w0 = -0.5f * t + t2 - 0.5f * t3;
    float w1 = 1.0f - 2.5f * t2 + 1.5f * t3;
    float w2 = 0.5f * t + 2.0f * t2 - 1.5f * t3;
    float w3 = -0.5f * t2 + 0.5f * t3;
    float cc[NCP] = {0.f, 0.f, 0.f, 0.f, 0.f, 0.f};
    cc[((bi - 1) % NCP + NCP) % NCP] += w0;
    cc[(bi % NCP + NCP) % NCP]       += w1;
    cc[((bi + 1) % NCP + NCP) % NCP] += w2;
    cc[((bi + 2) % NCP + NCP) % NCP] += w3;
    for (int j = 0; j < NCP; ++j) c4[j][tid] = cc[j];
  }

  f32x4 acc[4][4];
#pragma unroll
  for (int m = 0; m < 4; ++m)
#pragma unroll
    for (int n = 0; n < 4; ++n) acc[m][n] = (f32x4){0.f, 0.f, 0.f, 0.f};

  // W staging: lane l -> LDS row (base + l>>3), linear 16B slot (l&7);
  // global source column pre-swizzled (slot xor row&7), rule #21.
  int swzcol = ((lane & 7) ^ (lane >> 3)) * 8;
  const unsigned short* wsrc =
      wb + (size_t)(bcol + wid * 8 + (lane >> 3)) * I_SZ + swzcol;
  // read-side swizzled base: slot = k-chunk ^ (row&7); row&7 == lane&7 here
  int lbase = (lane & 15) * 128 + (((lane >> 4) ^ (lane & 7)) & 7) * 16;

  // A direct-global per-lane base: row = brow + wr*64 + m*16 + (lane&15),
  // k = ks*64 + kk*32 + (lane>>4)*8  (xb is linear; no swizzle on A)
  const unsigned short* xA =
      xb + (size_t)(brow + wr * 64 + (lane & 15)) * I_SZ + (lane >> 4) * 8;

  auto STAGE_W = [&](int ks, int j, int slot) {
    const unsigned short* ws = wsrc + (size_t)j * O_SZ * I_SZ + ks * BK;
#pragma unroll
    for (int p = 0; p < 2; ++p)
      gload_lds16(ws + (size_t)p * 64 * I_SZ,
                  &Wbuf[slot][(wid * 8 + p * 64) * BK]);
  };

  // prologue: first two W tiles in flight; drain c4 writes before barrier 0
  STAGE_W(0, 0, 0);
  STAGE_W(0, 1, 1);
  asm volatile("s_waitcnt lgkmcnt(0)" ::: "memory");  // c4 visible at barrier

  for (int ks = 0; ks < 16; ++ks) {
    // ---- A fragments: once per ks, straight from global, reused 6x ----
    bf16x8 afr[4][2];
    const unsigned short* xAk = xA + ks * 64;
#pragma unroll
    for (int m = 0; m < 4; ++m)
#pragma unroll
      for (int kk = 0; kk < 2; ++kk)
        afr[m][kk] = *reinterpret_cast<const bf16x8*>(
            xAk + (size_t)m * 16 * I_SZ + kk * 32);
    __builtin_amdgcn_sched_barrier(0);  // pin A-issue before the j brackets

#pragma unroll
    for (int j = 0; j < NCP; ++j) {
      // ---- bracket: counted vmcnt -> barrier (W(g) resident block-wide) ----
      if (ks == 15 && j == 5)
        asm volatile("s_waitcnt vmcnt(0)" ::: "memory");
      else if (j < 2)
        asm volatile("s_waitcnt vmcnt(10)" ::: "memory");
      else
        asm volatile("s_waitcnt vmcnt(2)" ::: "memory");
      __builtin_amdgcn_sched_barrier(0);
      __builtin_amdgcn_s_barrier();
      __builtin_amdgcn_sched_barrier(0);

      // ---- stage W for iter+2 (slot (j+2)%3 was last read at iter-1) ----
      if (ks < 15 || j < 4) {
        int jn = j + 2, ksn = ks;
        if (jn >= NCP) { jn -= NCP; ksn = ks + 1; }
        STAGE_W(ksn, jn, (j + 2) % 3);
      }

      // ---- B fragments + fold coefficients ----
      const char* Wb = (const char*)&Wbuf[j % 3][0];
      bf16x8 bfr[4][2];
#pragma unroll
      for (int n = 0; n < 4; ++n)
#pragma unroll
        for (int kk = 0; kk < 2; ++kk)
          bfr[n][kk] = *reinterpret_cast<const bf16x8*>(
              Wb + (wc * 64 + n * 16) * 128 + (lbase ^ (kk << 6)));
      f32x4 cv[4];
#pragma unroll
      for (int m = 0; m < 4; ++m)
        cv[m] = *reinterpret_cast<const f32x4*>(
            &c4[j][wr * 64 + m * 16 + (lane >> 4) * 4]);

      // ---- MFMA + immediate fold (no part[] array) ----
      __builtin_amdgcn_s_setprio(1);
#pragma unroll
      for (int m = 0; m < 4; ++m)
#pragma unroll
        for (int n = 0; n < 4; ++n) {
          f32x4 p = __builtin_amdgcn_mfma_f32_16x16x32_bf16(
              afr[m][0], bfr[n][0], (f32x4){0.f, 0.f, 0.f, 0.f}, 0, 0, 0);
          p = __builtin_amdgcn_mfma_f32_16x16x32_bf16(
              afr[m][1], bfr[n][1], p, 0, 0, 0);
          acc[m][n] += cv[m] * p;
        }
      __builtin_amdgcn_s_setprio(0);
    }
  }

  // ---- epilogue: bias mix + store (f32) ----
#pragma unroll
  for (int n = 0; n < 4; ++n) {
    int col = bcol + wc * 64 + n * 16 + (lane & 15);
    float b6[NCP];
#pragma unroll
    for (int j = 0; j < NCP; ++j) b6[j] = bias[j * O_SZ + col];
#pragma unroll
    for (int m = 0; m < 4; ++m) {
#pragma unroll
      for (int r = 0; r < 4; ++r) {
        int rloc = wr * 64 + m * 16 + (lane >> 4) * 4 + r;
        float s = 0.f;
#pragma unroll
        for (int j = 0; j < NCP; ++j) s += c4[j][rloc] * b6[j];
        out[(size_t)(brow + rloc) * O_SZ + col] = acc[m][n][r] + s;
      }
    }
  }
}

extern "C" void kernel_launch(void* const* d_in, const int* in_sizes, int n_in,
                              void* d_out, int out_size, void* d_ws, size_t ws_size,
                              hipStream_t stream) {
  (void)in_sizes; (void)n_in; (void)out_size; (void)ws_size;
  const float* x     = (const float*)d_in[0];  // [B, I]
  const float* phase = (const float*)d_in[1];  // [B]
  const float* w     = (const float*)d_in[2];  // [C, O, I]
  const float* bias  = (const float*)d_in[3];  // [C, O]
  float* out = (float*)d_out;                  // [B, O] f32

  unsigned short* xb = (unsigned short*)d_ws;                       // 16 MB
  unsigned short* wb = (unsigned short*)((char*)d_ws +
                        (size_t)B_SZ * I_SZ * sizeof(unsigned short));  // 12 MB

  cvt_f32_to_bf16<<<2048, 256, 0, stream>>>(x, xb, B_SZ * I_SZ / 4);
  cvt_f32_to_bf16<<<1536, 256, 0, stream>>>(w, wb, NCP * O_SZ * I_SZ / 4);

  dim3 grid((B_SZ / BM) * (O_SZ / BN));  // 32*8 = 256
  pfl_gemm<<<grid, 512, 0, stream>>>(xb, wb, phase, bias, out);
}

// Round 10
// 174.279 us; speedup vs baseline: 1.0038x; 1.0038x over previous
//
#include <hip/hip_runtime.h>
#include <hip/hip_bf16.h>
#include <math.h>

#define B_SZ 8192
#define I_SZ 1024
#define O_SZ 1024
#define NCP  6

typedef __attribute__((ext_vector_type(8))) short bf16x8;
typedef __attribute__((ext_vector_type(4))) float f32x4;

__device__ __forceinline__ unsigned short f2bf(float f) {
  union { float f; unsigned int u; } v; v.f = f;
  unsigned int u = v.u;
  u += 0x7FFFu + ((u >> 16) & 1u);   // round-to-nearest-even
  return (unsigned short)(u >> 16);
}

__global__ void cvt_f32_to_bf16(const float* __restrict__ src,
                                unsigned short* __restrict__ dst, int n4) {
  int idx = blockIdx.x * blockDim.x + threadIdx.x;
  int stride = gridDim.x * blockDim.x;
  for (int i = idx; i < n4; i += stride) {
    float4 v = reinterpret_cast<const float4*>(src)[i];
    ushort4 o;
    o.x = f2bf(v.x); o.y = f2bf(v.y); o.z = f2bf(v.z); o.w = f2bf(v.w);
    reinterpret_cast<ushort4*>(dst)[i] = o;
  }
}

__device__ __forceinline__ void gload_lds16(const void* g, void* l) {
  __builtin_amdgcn_global_load_lds(
      (const __attribute__((address_space(1))) void*)g,
      (__attribute__((address_space(3))) void*)l, 16, 0, 0);
}

#define BM 256
#define BN 128
#define BK 64

// out[b,o] = sum_j c[b,j] * ( sum_i W[j,o,i]*x[b,i] + bias[j,o] )
// ks-outer / j-inner: A-fragments loaded once per ks from global (L3-hot)
// into registers, reused across all 6 j; LDS carries only W (ring of 3
// slots) + c table. ROUND-10 FIX: launch_bounds (512,1) -- round 9's (512,2)
// capped VGPR at 128 while live set is ~175, forcing scratch spills
// (WRITE_SIZE 62->167 MB was spill traffic). Grid is exactly 1 block/CU,
// so the looser bound costs no occupancy.
__global__ __launch_bounds__(512, 1) void pfl_gemm(
    const unsigned short* __restrict__ xb,
    const unsigned short* __restrict__ wb,
    const float* __restrict__ phase,
    const float* __restrict__ bias,
    float* __restrict__ out) {
  __shared__ __align__(16) unsigned short Wbuf[3][BN * BK];  // 3x16 KB
  __shared__ __align__(16) float c4[NCP][BM];                // 6 KB

  const int nbn = O_SZ / BN;  // 8
  int bid = (int)blockIdx.x;  // 256 blocks (divisible by 8)
  int swz = (bid & 7) * 32 + (bid >> 3);  // bijective XCD remap
  int brow = (swz / nbn) * BM;
  int bcol = (swz % nbn) * BN;

  int tid = (int)threadIdx.x;
  int lane = tid & 63;
  int wid = tid >> 6;        // 0..7
  int wr = wid >> 1;         // 0..3 (M)
  int wc = wid & 1;          // 0..1 (N)

  // ---- Catmull-Rom coefficients, layout [j][row] for vectorized folds ----
  if (tid < BM) {
    float ph = phase[brow + tid];
    const float two_pi = 6.2831855f;
    float pm = fmodf(ph, two_pi);              // ph >= 0 -> trunc == floor mod
    float pos = pm * (float)(6.0 / 6.283185307179586);
    float base = floorf(pos);
    int bi = (int)base;
    float t = pos - base;
    float t2 = t * t, t3 = t2 * t;
    float w0 = -0.5f * t + t2 - 0.5f * t3;
    float w1 = 1.0f - 2.5f * t2 + 1.5f * t3;
    float w2 = 0.5f * t + 2.0f * t2 - 1.5f * t3;
    float w3 = -0.5f * t2 + 0.5f * t3;
    float cc[NCP] = {0.f, 0.f, 0.f, 0.f, 0.f, 0.f};
    cc[((bi - 1) % NCP + NCP) % NCP] += w0;
    cc[(bi % NCP + NCP) % NCP]       += w1;
    cc[((bi + 1) % NCP + NCP) % NCP] += w2;
    cc[((bi + 2) % NCP + NCP) % NCP] += w3;
    for (int j = 0; j < NCP; ++j) c4[j][tid] = cc[j];
  }

  f32x4 acc[4][4];
#pragma unroll
  for (int m = 0; m < 4; ++m)
#pragma unroll
    for (int n = 0; n < 4; ++n) acc[m][n] = (f32x4){0.f, 0.f, 0.f, 0.f};

  // W staging: lane l -> LDS row (base + l>>3), linear 16B slot (l&7);
  // global source column pre-swizzled (slot xor row&7), rule #21.
  int swzcol = ((lane & 7) ^ (lane >> 3)) * 8;
  const unsigned short* wsrc =
      wb + (size_t)(bcol + wid * 8 + (lane >> 3)) * I_SZ + swzcol;
  // read-side swizzled base: slot = k-chunk ^ (row&7); row&7 == lane&7 here
  int lbase = (lane & 15) * 128 + (((lane >> 4) ^ (lane & 7)) & 7) * 16;

  // A direct-global per-lane base: row = brow + wr*64 + m*16 + (lane&15),
  // k = ks*64 + kk*32 + (lane>>4)*8  (xb is linear; no swizzle on A)
  const unsigned short* xA =
      xb + (size_t)(brow + wr * 64 + (lane & 15)) * I_SZ + (lane >> 4) * 8;

  auto STAGE_W = [&](int ks, int j, int slot) {
    const unsigned short* ws = wsrc + (size_t)j * O_SZ * I_SZ + ks * BK;
#pragma unroll
    for (int p = 0; p < 2; ++p)
      gload_lds16(ws + (size_t)p * 64 * I_SZ,
                  &Wbuf[slot][(wid * 8 + p * 64) * BK]);
  };

  // prologue: first two W tiles in flight; drain c4 writes before barrier 0
  STAGE_W(0, 0, 0);
  STAGE_W(0, 1, 1);
  asm volatile("s_waitcnt lgkmcnt(0)" ::: "memory");  // c4 visible at barrier

  for (int ks = 0; ks < 16; ++ks) {
    // ---- A fragments: once per ks, straight from global, reused 6x ----
    bf16x8 afr[4][2];
    const unsigned short* xAk = xA + ks * 64;
#pragma unroll
    for (int m = 0; m < 4; ++m)
#pragma unroll
      for (int kk = 0; kk < 2; ++kk)
        afr[m][kk] = *reinterpret_cast<const bf16x8*>(
            xAk + (size_t)m * 16 * I_SZ + kk * 32);
    __builtin_amdgcn_sched_barrier(0);  // pin A-issue before the j brackets

#pragma unroll
    for (int j = 0; j < NCP; ++j) {
      // ---- bracket: counted vmcnt -> barrier (W(g) resident block-wide) ----
      if (ks == 15 && j == 5)
        asm volatile("s_waitcnt vmcnt(0)" ::: "memory");
      else if (j < 2)
        asm volatile("s_waitcnt vmcnt(10)" ::: "memory");
      else
        asm volatile("s_waitcnt vmcnt(2)" ::: "memory");
      __builtin_amdgcn_sched_barrier(0);
      __builtin_amdgcn_s_barrier();
      __builtin_amdgcn_sched_barrier(0);

      // ---- stage W for iter+2 (slot (j+2)%3 was last read at iter-1) ----
      if (ks < 15 || j < 4) {
        int jn = j + 2, ksn = ks;
        if (jn >= NCP) { jn -= NCP; ksn = ks + 1; }
        STAGE_W(ksn, jn, (j + 2) % 3);
      }

      // ---- B fragments + fold coefficients ----
      const char* Wb = (const char*)&Wbuf[j % 3][0];
      bf16x8 bfr[4][2];
#pragma unroll
      for (int n = 0; n < 4; ++n)
#pragma unroll
        for (int kk = 0; kk < 2; ++kk)
          bfr[n][kk] = *reinterpret_cast<const bf16x8*>(
              Wb + (wc * 64 + n * 16) * 128 + (lbase ^ (kk << 6)));
      f32x4 cv[4];
#pragma unroll
      for (int m = 0; m < 4; ++m)
        cv[m] = *reinterpret_cast<const f32x4*>(
            &c4[j][wr * 64 + m * 16 + (lane >> 4) * 4]);

      // ---- MFMA + immediate fold (no part[] array) ----
      __builtin_amdgcn_s_setprio(1);
#pragma unroll
      for (int m = 0; m < 4; ++m)
#pragma unroll
        for (int n = 0; n < 4; ++n) {
          f32x4 p = __builtin_amdgcn_mfma_f32_16x16x32_bf16(
              afr[m][0], bfr[n][0], (f32x4){0.f, 0.f, 0.f, 0.f}, 0, 0, 0);
          p = __builtin_amdgcn_mfma_f32_16x16x32_bf16(
              afr[m][1], bfr[n][1], p, 0, 0, 0);
          acc[m][n] += cv[m] * p;
        }
      __builtin_amdgcn_s_setprio(0);
    }
  }

  // ---- epilogue: bias mix + store (f32) ----
#pragma unroll
  for (int n = 0; n < 4; ++n) {
    int col = bcol + wc * 64 + n * 16 + (lane & 15);
    float b6[NCP];
#pragma unroll
    for (int j = 0; j < NCP; ++j) b6[j] = bias[j * O_SZ + col];
#pragma unroll
    for (int m = 0; m < 4; ++m) {
#pragma unroll
      for (int r = 0; r < 4; ++r) {
        int rloc = wr * 64 + m * 16 + (lane >> 4) * 4 + r;
        float s = 0.f;
#pragma unroll
        for (int j = 0; j < NCP; ++j) s += c4[j][rloc] * b6[j];
        out[(size_t)(brow + rloc) * O_SZ + col] = acc[m][n][r] + s;
      }
    }
  }
}

extern "C" void kernel_launch(void* const* d_in, const int* in_sizes, int n_in,
                              void* d_out, int out_size, void* d_ws, size_t ws_size,
                              hipStream_t stream) {
  (void)in_sizes; (void)n_in; (void)out_size; (void)ws_size;
  const float* x     = (const float*)d_in[0];  // [B, I]
  const float* phase = (const float*)d_in[1];  // [B]
  const float* w     = (const float*)d_in[2];  // [C, O, I]
  const float* bias  = (const float*)d_in[3];  // [C, O]
  float* out = (float*)d_out;                  // [B, O] f32

  unsigned short* xb = (unsigned short*)d_ws;                       // 16 MB
  unsigned short* wb = (unsigned short*)((char*)d_ws +
                        (size_t)B_SZ * I_SZ * sizeof(unsigned short));  // 12 MB

  cvt_f32_to_bf16<<<2048, 256, 0, stream>>>(x, xb, B_SZ * I_SZ / 4);
  cvt_f32_to_bf16<<<1536, 256, 0, stream>>>(w, wb, NCP * O_SZ * I_SZ / 4);

  dim3 grid((B_SZ / BM) * (O_SZ / BN));  // 32*8 = 256
  pfl_gemm<<<grid, 512, 0, stream>>>(xb, wb, phase, bias, out);
}